// Round 1
// 501.332 us; speedup vs baseline: 1.0018x; 1.0018x over previous
//
#include <hip/hip_runtime.h>
#include <math.h>

// ---------------------------------------------------------------------------
// GATv2 x3 + LN + graph max-pool + MLP.
// Round 10: k_agg software-pipelined one stage deeper. rocprof showed
// VALUBusy=61%, HBM=22%, MfmaUtil=0 -> gather-latency-bound: the xl row
// gather was issued and consumed in the same iteration. Now: edge-record
// (e4) prefetch at distance 2, xl-gather prefetch at distance 1, so each
// gather has a full compute phase (~44 VALU ops) to complete. VGPR grows
// 28 -> ~48 (still <=64, occupancy cap unchanged at 8 waves/SIMD).
// Everything else identical to R9 (binned CSR prepass, swapped-operand
// MFMA GEMM, packed per-lane score params).
// ---------------------------------------------------------------------------

#define LN_EPS 1e-5f
#define LOG2E 1.44269504088896340736f
#define CHUNK 4096
#define BCAP 8192  // records per staging bucket (avg 4096)

typedef short bf16x8 __attribute__((ext_vector_type(8)));
typedef float f32x4 __attribute__((ext_vector_type(4)));

static __device__ __forceinline__ unsigned short f2bf(float f) {
  unsigned int u = __float_as_uint(f);
  u += 0x7fffu + ((u >> 16) & 1u);  // RNE
  return (unsigned short)(u >> 16);
}

// sum+broadcast over each 8-lane group: quad xor1, quad xor2, row_half_mirror
static __device__ __forceinline__ float dpp_sum8(float v) {
  int x;
  x = __builtin_amdgcn_update_dpp(0, __float_as_int(v), 0x0B1, 0xf, 0xf, true);  // quad_perm 1,0,3,2
  v += __int_as_float(x);
  x = __builtin_amdgcn_update_dpp(0, __float_as_int(v), 0x04E, 0xf, 0xf, true);  // quad_perm 2,3,0,1
  v += __int_as_float(x);
  x = __builtin_amdgcn_update_dpp(0, __float_as_int(v), 0x141, 0xf, 0xf, true);  // row_half_mirror
  v += __int_as_float(x);
  return v;
}

// ---------------- binned CSR build ----------------

__global__ __launch_bounds__(256) void k_binA(const int* __restrict__ ei, const float* __restrict__ ea,
                                              int* __restrict__ gcnt, float4* __restrict__ staged,
                                              int E, int nbuk) {
  __shared__ int hist[256];
  __shared__ int basebuf[256];
  int t = threadIdx.x;
  int e0 = blockIdx.x * CHUNK;

  hist[t] = 0;
  __syncthreads();
#pragma unroll
  for (int i = 0; i < CHUNK / 256; ++i) {
    int e = e0 + i * 256 + t;
    if (e < E) atomicAdd(&hist[ei[E + e] >> 8], 1);
  }
  __syncthreads();
  int h = hist[t];
  if (t < nbuk && h > 0) basebuf[t] = t * BCAP + atomicAdd(&gcnt[t], h);
  hist[t] = 0;
  __syncthreads();
#pragma unroll
  for (int i = 0; i < CHUNK / 256; ++i) {
    int e = e0 + i * 256 + t;
    if (e < E) {
      int s = ei[e];
      int d = ei[E + e];
      int b = d >> 8;
      int r = atomicAdd(&hist[b], 1);
      float4 rec;
      rec.x = ea[e * 3 + 0];
      rec.y = ea[e * 3 + 1];
      rec.z = ea[e * 3 + 2];
      rec.w = __int_as_float(s | (d << 16));
      staged[basebuf[b] + r] = rec;
    }
  }
}

__global__ void k_bscan(const int* __restrict__ gcnt, int* __restrict__ bukStart,
                        int* __restrict__ offs, int N, int nbuk, int EP) {
  __shared__ int sh[256];
  int t = threadIdx.x;
  int nodes = (t < nbuk) ? min(256, N - t * 256) : 0;
  int v = (t < nbuk) ? gcnt[t] + nodes : 0;
  sh[t] = v;
  __syncthreads();
  for (int d = 1; d < 256; d <<= 1) {
    int add = (t >= d) ? sh[t - d] : 0;
    __syncthreads();
    sh[t] += add;
    __syncthreads();
  }
  if (t < nbuk) bukStart[t] = sh[t] - v;
  if (t == 0) offs[N] = EP;
}

__global__ __launch_bounds__(256) void k_binB(const float4* __restrict__ staged,
                                              const int* __restrict__ gcnt,
                                              const int* __restrict__ bukStart,
                                              float4* __restrict__ e4,
                                              int* __restrict__ offs, int N) {
  __shared__ int hist[256], cur[256], begS[256], sh[256];
  int t = threadIdx.x;
  int b = blockIdx.x;
  int n0 = b * 256;
  int nn = min(256, N - n0);
  int m = gcnt[b];
  size_t sbase = (size_t)b * BCAP;

  hist[t] = 0;
  __syncthreads();
  for (int p = t; p < m; p += 256) {
    unsigned int u = (unsigned int)__float_as_int(staged[sbase + p].w);
    atomicAdd(&hist[(int)(u >> 16) - n0], 1);
  }
  __syncthreads();
  int v = (t < nn) ? hist[t] + 1 : 0;
  sh[t] = v;
  __syncthreads();
  for (int d = 1; d < 256; d <<= 1) {
    int add = (t >= d) ? sh[t - d] : 0;
    __syncthreads();
    sh[t] += add;
    __syncthreads();
  }
  if (t < nn) {
    int base = bukStart[b] + sh[t] - v;
    cur[t] = base;
    begS[t] = base;
    offs[n0 + t] = base;
  }
  __syncthreads();
  for (int p = t; p < m; p += 256) {
    float4 rec = staged[sbase + p];
    unsigned int u = (unsigned int)__float_as_int(rec.w);
    int pos = atomicAdd(&cur[(int)(u >> 16) - n0], 1);
    rec.w = __int_as_float((int)(u & 0xffffu) * 256);
    e4[pos] = rec;
  }
  __syncthreads();
  if (t < nn) {
    int beg = begS[t], last = cur[t];  // cur == self-loop slot after placement
    float s0 = 0.f, s1 = 0.f, s2 = 0.f;
    for (int p = beg; p < last; ++p) {
      float4 r = e4[p];
      s0 += r.x;
      s1 += r.y;
      s2 += r.z;
    }
    float invc = 1.0f / fmaxf((float)(last - beg), 1.0f);
    float4 r;
    r.x = s0 * invc;
    r.y = s1 * invc;
    r.z = s2 * invc;
    r.w = __int_as_float((n0 + t) * 256);
    e4[last] = r;
  }
}

// ---------------- converters / param packing ----------------

__global__ void k_convx(const float* __restrict__ x, unsigned short* __restrict__ xb, int n) {
  int i = (blockIdx.x * blockDim.x + threadIdx.x) * 4;
  if (i >= n) return;
  float4 v = *(const float4*)&x[i];
  ushort4 o;
  o.x = f2bf(v.x); o.y = f2bf(v.y); o.z = f2bf(v.z); o.w = f2bf(v.w);
  *(ushort4*)&xb[i] = o;
}

__global__ void k_convW(const float* __restrict__ w0, const float* __restrict__ w1,
                        const float* __restrict__ w2, const float* __restrict__ w3,
                        const float* __restrict__ w4, const float* __restrict__ w5,
                        unsigned short* __restrict__ dst) {
  const float* srcs[6] = {w0, w1, w2, w3, w4, w5};
  const float* s = srcs[blockIdx.y];
  int i = blockIdx.x * 256 + threadIdx.x;  // 0..16383
  dst[(size_t)blockIdx.y * 16384 + i] = f2bf(s[i]);
}

// per-layer, per-lane score params: tab[l][sl][16] = {wea[4], web[4], wec[4], att*LOG2E[4]}
__global__ void k_pack(const float* __restrict__ We0, const float* __restrict__ att0,
                       const float* __restrict__ We1, const float* __restrict__ att1,
                       const float* __restrict__ We2, const float* __restrict__ att2,
                       float* __restrict__ tab) {
  int l = blockIdx.x;   // 3
  int t = threadIdx.x;  // 32 (= sl)
  const float* We = (l == 0) ? We0 : ((l == 1) ? We1 : We2);
  const float* att = (l == 0) ? att0 : ((l == 1) ? att1 : att2);
  float* o = tab + (size_t)l * 512 + t * 16;
#pragma unroll
  for (int j = 0; j < 4; ++j) {
    o[j] = We[(t * 4 + j) * 3 + 0];
    o[4 + j] = We[(t * 4 + j) * 3 + 1];
    o[8 + j] = We[(t * 4 + j) * 3 + 2];
    o[12 + j] = att[t * 4 + j] * LOG2E;
  }
}

// ---------------- MFMA GEMM (swapped operands): out_bf16[n][j] = bias[j] + x[n]·W[j] ----------------
// A=W rows (channel jt*16+m), B=x rows (node row0+m); D row=channel q*4+r,
// col=node m -> lane holds 4 contiguous channels -> uint2 packed stores.
__global__ __launch_bounds__(256) void k_gemm_mfma(const unsigned short* __restrict__ xb,
                                                   const unsigned short* __restrict__ Wb,
                                                   const float* __restrict__ bl, const float* __restrict__ br,
                                                   unsigned short* __restrict__ xlb,
                                                   unsigned short* __restrict__ xrb, int N) {
  int wave = threadIdx.x >> 6;
  int lane = threadIdx.x & 63;
  int which = blockIdx.y;
  const unsigned short* W = Wb + (size_t)which * 16384;
  const float* bias = which ? br : bl;
  unsigned short* out = which ? xrb : xlb;

  int row0 = (blockIdx.x * 4 + wave) * 16;
  if (row0 >= N) return;
  int m = lane & 15;
  int q = lane >> 4;

  int brow = row0 + m;
  if (brow >= N) brow = N - 1;
  const unsigned short* xrow = xb + (size_t)brow * 128 + q * 8;

  bf16x8 bfrag[4];
#pragma unroll
  for (int kt = 0; kt < 4; ++kt) bfrag[kt] = *(const bf16x8*)(xrow + kt * 32);

  f32x4 acc[8];
#pragma unroll
  for (int jt = 0; jt < 8; ++jt) acc[jt] = (f32x4){0.f, 0.f, 0.f, 0.f};

  const unsigned short* wbase = W + (size_t)m * 128 + q * 8;
#pragma unroll
  for (int kt = 0; kt < 4; ++kt) {
#pragma unroll
    for (int jt = 0; jt < 8; ++jt) {
      bf16x8 a = *(const bf16x8*)(wbase + (size_t)jt * 16 * 128 + kt * 32);
      acc[jt] = __builtin_amdgcn_mfma_f32_16x16x32_bf16(a, bfrag[kt], acc[jt], 0, 0, 0);
    }
  }

  int node = row0 + m;
  if (node < N) {
    unsigned short* orow = out + (size_t)node * 128 + q * 4;
#pragma unroll
    for (int jt = 0; jt < 8; ++jt) {
      float4 bs = *(const float4*)&bias[jt * 16 + q * 4];
      uint2 pack;
      pack.x = (unsigned int)f2bf(acc[jt][0] + bs.x) | ((unsigned int)f2bf(acc[jt][1] + bs.y) << 16);
      pack.y = (unsigned int)f2bf(acc[jt][2] + bs.z) | ((unsigned int)f2bf(acc[jt][3] + bs.w) << 16);
      *(uint2*)(orow + jt * 16) = pack;
    }
  }
}

// ---------------- fused: score + softmax(exp2) + weighted agg + epilogue ----------------
// one wave per node; lanes 0-31 = edge p, lanes 32-63 = edge p+1 (same node);
// each lane owns 4 channels c = (lane&31)*4; head group = 8 lanes.
// R10: 2-deep pipeline -- e4 record prefetched at distance 2, xl gather
// prefetched at distance 1 so VMEM latency hides under the compute phase.
__global__ __launch_bounds__(256) void k_agg(const unsigned short* __restrict__ xlb,
                                             const unsigned short* __restrict__ xrb,
                                             const float4* __restrict__ e4,
                                             const int* __restrict__ offs,
                                             const float* __restrict__ scoreTab,
                                             const float* __restrict__ bo,
                                             const float* __restrict__ lng, const float* __restrict__ lnb,
                                             unsigned short* __restrict__ xnext_bf,
                                             float* __restrict__ emb, int last, int N) {
  int w = (blockIdx.x * blockDim.x + threadIdx.x) >> 6;
  if (w >= N) return;
  int lane = threadIdx.x & 63;
  int half = lane >> 5;
  int sl = lane & 31;
  int c = sl * 4;
  unsigned int c2 = (unsigned int)(c * 2);  // byte offset into bf16 row
  int beg = offs[w], end = offs[w + 1];
  int cnt = end - beg;

  // packed per-lane params
  f32x4 xr4, wea, web, wec, at4;
  {
    const float4* tp = (const float4*)(scoreTab + (size_t)sl * 16);
    float4 pa = tp[0], pb = tp[1], pc = tp[2], pt = tp[3];
    wea[0] = pa.x; wea[1] = pa.y; wea[2] = pa.z; wea[3] = pa.w;
    web[0] = pb.x; web[1] = pb.y; web[2] = pb.z; web[3] = pb.w;
    wec[0] = pc.x; wec[1] = pc.y; wec[2] = pc.z; wec[3] = pc.w;
    at4[0] = pt.x; at4[1] = pt.y; at4[2] = pt.z; at4[3] = pt.w;
    uint2 vr = *(const uint2*)&xrb[(size_t)w * 128 + c];
    xr4[0] = __uint_as_float(vr.x << 16);
    xr4[1] = __uint_as_float(vr.x & 0xffff0000u);
    xr4[2] = __uint_as_float(vr.y << 16);
    xr4[3] = __uint_as_float(vr.y & 0xffff0000u);
  }

  const char* xlB = (const char*)xlb;
  const char* e4B = (const char*)e4;
  unsigned int lastoff = (unsigned int)(end - 1) << 4;

  float l = 0.f;
  f32x4 acc = {0.f, 0.f, 0.f, 0.f};

  int T = (cnt + 1) >> 1;  // pair iterations

  // ---- pipeline prologue: rec at dist 0 and 1, gather for dist 0 ----
  unsigned int off0 = (unsigned int)(beg + half) << 4;
  if (off0 > lastoff) off0 = lastoff;  // cnt==1, half 1 clamps
  float4 eC = *(const float4*)(e4B + off0);
  unsigned int offP = off0 + 32u;
  if (offP > lastoff) offP = lastoff;
  float4 eN = *(const float4*)(e4B + offP);
  uint2 vC = *(const uint2*)(xlB + ((unsigned int)__float_as_int(eC.w) + c2));

  // one edge: unpack gather, score, exp2, accumulate. `valid` folds for the
  // unmasked path (compile-time true at call sites in the steady loop).
  auto compute = [&](const float4& e, uint2 v, bool valid) {
    f32x4 xl4;
    xl4[0] = __uint_as_float(v.x << 16);
    xl4[1] = __uint_as_float(v.x & 0xffff0000u);
    xl4[2] = __uint_as_float(v.y << 16);
    xl4[3] = __uint_as_float(v.y & 0xffff0000u);
    f32x4 t = xr4 + wea * e.x + web * e.y + wec * e.z + xl4;
    t[0] = fmaxf(t[0], 0.2f * t[0]);
    t[1] = fmaxf(t[1], 0.2f * t[1]);
    t[2] = fmaxf(t[2], 0.2f * t[2]);
    t[3] = fmaxf(t[3], 0.2f * t[3]);
    float s = t[0] * at4[0] + t[1] * at4[1] + t[2] * at4[2] + t[3] * at4[3];
    float wgt = __builtin_amdgcn_exp2f(dpp_sum8(s));
    if (!valid) wgt = 0.f;
    l += wgt;
    acc += xl4 * wgt;
  };

  // ---- steady state: prefetch rec(i+2) and gather(i+1), compute i ----
#pragma unroll 2
  for (int it = 0; it < T - 2; ++it) {
    unsigned int off2 = offP + 32u;
    if (off2 > lastoff) off2 = lastoff;
    float4 eNN = *(const float4*)(e4B + off2);
    uint2 vN = *(const uint2*)(xlB + ((unsigned int)__float_as_int(eN.w) + c2));
    compute(eC, vC, true);
    eC = eN; vC = vN; eN = eNN; offP = off2;
  }
  // pair T-2 (always fully valid when T >= 2)
  if (T >= 2) {
    uint2 vN = *(const uint2*)(xlB + ((unsigned int)__float_as_int(eN.w) + c2));
    compute(eC, vC, true);
    eC = eN; vC = vN;
  }
  // pair T-1 (masked: odd cnt leaves half==1 invalid)
  {
    int idx = 2 * (T - 1) + half;
    compute(eC, vC, idx < cnt);
  }

  // combine halves
  l += __shfl_xor(l, 32);
  acc[0] += __shfl_xor(acc[0], 32);
  acc[1] += __shfl_xor(acc[1], 32);
  acc[2] += __shfl_xor(acc[2], 32);
  acc[3] += __shfl_xor(acc[3], 32);

  float inv = 1.0f / l;
  f32x4 o;
  const float4 bo4 = *(const float4*)&bo[c];
  o[0] = acc[0] * inv + bo4.x;
  o[1] = acc[1] * inv + bo4.y;
  o[2] = acc[2] * inv + bo4.z;
  o[3] = acc[3] * inv + bo4.w;

  if (last) {
    if (half == 0) {
      float4 st = {o[0], o[1], o[2], o[3]};
      *(float4*)&emb[(size_t)w * 128 + c] = st;
    }
  } else {
    f32x4 r;
    r[0] = fmaxf(o[0], 0.f);
    r[1] = fmaxf(o[1], 0.f);
    r[2] = fmaxf(o[2], 0.f);
    r[3] = fmaxf(o[3], 0.f);
    float s = r[0] + r[1] + r[2] + r[3];
    s += __shfl_xor(s, 1);
    s += __shfl_xor(s, 2);
    s += __shfl_xor(s, 4);
    s += __shfl_xor(s, 8);
    s += __shfl_xor(s, 16);
    float mu = s * 0.0078125f;  // /128
    f32x4 d;
    d[0] = r[0] - mu;
    d[1] = r[1] - mu;
    d[2] = r[2] - mu;
    d[3] = r[3] - mu;
    float v2 = d[0] * d[0] + d[1] * d[1] + d[2] * d[2] + d[3] * d[3];
    v2 += __shfl_xor(v2, 1);
    v2 += __shfl_xor(v2, 2);
    v2 += __shfl_xor(v2, 4);
    v2 += __shfl_xor(v2, 8);
    v2 += __shfl_xor(v2, 16);
    float var = v2 * 0.0078125f;
    float rstd = rsqrtf(var + LN_EPS);
    if (half == 0) {
      const float4 g4 = *(const float4*)&lng[c];
      const float4 b4 = *(const float4*)&lnb[c];
      float o0 = d[0] * rstd * g4.x + b4.x;
      float o1 = d[1] * rstd * g4.y + b4.y;
      float o2 = d[2] * rstd * g4.z + b4.z;
      float o3 = d[3] * rstd * g4.w + b4.w;
      uint2 pack;
      pack.x = (unsigned int)f2bf(o0) | ((unsigned int)f2bf(o1) << 16);
      pack.y = (unsigned int)f2bf(o2) | ((unsigned int)f2bf(o3) << 16);
      *(uint2*)&xnext_bf[(size_t)w * 128 + c] = pack;
    }
  }
}

// ---------------- graph max-pool (relu implicit: atomicMax vs 0-init) ----------------
__global__ void k_pool(const float* __restrict__ emb, const int* __restrict__ batch,
                       float* __restrict__ pooled, int N) {
  int c = threadIdx.x & 127;
  int half = threadIdx.x >> 7;
  int base = blockIdx.x * 64 + half;
  int limit = min(blockIdx.x * 64 + 64, N);
  float cur = 0.f;
  int curg = -1;
  for (int n = base; n < limit; n += 2) {
    int g = batch[n];
    if (g != curg) {
      if (curg >= 0) atomicMax((unsigned int*)&pooled[curg * 128 + c], __float_as_uint(cur));
      curg = g;
      cur = 0.f;
    }
    cur = fmaxf(cur, emb[(size_t)n * 128 + c]);
  }
  if (curg >= 0) atomicMax((unsigned int*)&pooled[curg * 128 + c], __float_as_uint(cur));
}

// ---------------- MLP: 128 -> 32 -> 32 -> 32 -> 1 ----------------
__global__ void k_mlp(const float* __restrict__ pooled,
                      const float* __restrict__ pw1, const float* __restrict__ pb1,
                      const float* __restrict__ pw2, const float* __restrict__ pb2,
                      const float* __restrict__ pw3, const float* __restrict__ pb3,
                      const float* __restrict__ pw4, const float* __restrict__ pb4,
                      float* __restrict__ out) {
  int g = blockIdx.x;
  int t = threadIdx.x;  // 64 threads
  __shared__ float buf1[32], buf2[32];
  if (t < 32) {
    float acc = pb1[t];
    for (int k = 0; k < 128; ++k) acc += pw1[t * 128 + k] * pooled[g * 128 + k];
    buf1[t] = fmaxf(acc, 0.f);
  }
  __syncthreads();
  if (t < 32) {
    float acc = pb2[t];
    for (int k = 0; k < 32; ++k) acc += pw2[t * 32 + k] * buf1[k];
    buf2[t] = fmaxf(acc, 0.f);
  }
  __syncthreads();
  if (t < 32) {
    float acc = pb3[t];
    for (int k = 0; k < 32; ++k) acc += pw3[t * 32 + k] * buf2[k];
    buf1[t] = fmaxf(acc, 0.f);
  }
  __syncthreads();
  if (t == 0) {
    float acc = pb4[0];
    for (int k = 0; k < 32; ++k) acc += pw4[k] * buf1[k];
    out[g] = acc;
  }
}

// ---------------------------------------------------------------------------

extern "C" void kernel_launch(void* const* d_in, const int* in_sizes, int n_in,
                              void* d_out, int out_size, void* d_ws, size_t ws_size,
                              hipStream_t stream) {
  const float* x_in = (const float*)d_in[0];
  const int* ei = (const int*)d_in[1];
  const int* batch = (const int*)d_in[2];
  const float* ea = (const float*)d_in[3];

  const int N = in_sizes[0] / 128;
  const int E = in_sizes[1] / 2;
  const int EP = E + N;
  const int G = out_size - N * 128;
  const int NBUK = (N + 255) / 256;

  const float *Wl[3], *bl[3], *Wr[3], *br[3], *We[3], *att[3], *bo[3];
  for (int l = 0; l < 3; ++l) {
    Wl[l] = (const float*)d_in[4 + 7 * l];
    bl[l] = (const float*)d_in[5 + 7 * l];
    Wr[l] = (const float*)d_in[6 + 7 * l];
    br[l] = (const float*)d_in[7 + 7 * l];
    We[l] = (const float*)d_in[8 + 7 * l];
    att[l] = (const float*)d_in[9 + 7 * l];
    bo[l] = (const float*)d_in[10 + 7 * l];
  }
  const float* lng[2] = {(const float*)d_in[25], (const float*)d_in[27]};
  const float* lnb[2] = {(const float*)d_in[26], (const float*)d_in[28]};
  const float* pw1 = (const float*)d_in[29];
  const float* pb1 = (const float*)d_in[30];
  const float* pw2 = (const float*)d_in[31];
  const float* pb2 = (const float*)d_in[32];
  const float* pw3 = (const float*)d_in[33];
  const float* pb3 = (const float*)d_in[34];
  const float* pw4 = (const float*)d_in[35];
  const float* pb4 = (const float*)d_in[36];

  char* base = (char*)d_ws;
  size_t cur = 0;
  auto carve = [&](size_t bytes) -> char* {
    char* p = base + cur;
    cur += (bytes + 255) & ~(size_t)255;
    return p;
  };
  unsigned short* xlb = (unsigned short*)carve((size_t)N * 128 * 2);
  unsigned short* xrb = (unsigned short*)carve((size_t)N * 128 * 2);
  unsigned short* xb = (unsigned short*)carve((size_t)N * 128 * 2);  // bf16 activations
  unsigned short* Wb = (unsigned short*)carve((size_t)6 * 16384 * 2);
  float4* e4 = (float4*)carve((size_t)EP * 16);
  float4* staged = (float4*)carve((size_t)NBUK * BCAP * 16);
  int* offs = (int*)carve((size_t)(N + 1) * 4);
  int* gcnt = (int*)carve((size_t)NBUK * 4);
  int* bukStart = (int*)carve((size_t)(NBUK + 1) * 4);
  float* scoreTab = (float*)carve((size_t)3 * 512 * 4);
  float* pooled = (float*)carve((size_t)G * 128 * 4);

  float* emb_out = (float*)d_out;
  float* mlp_out = (float*)d_out + (size_t)N * 128;

  hipMemsetAsync(gcnt, 0, (size_t)NBUK * 4, stream);
  hipMemsetAsync(pooled, 0, (size_t)G * 128 * 4, stream);

  k_binA<<<(E + CHUNK - 1) / CHUNK, 256, 0, stream>>>(ei, ea, gcnt, staged, E, NBUK);
  k_bscan<<<1, 256, 0, stream>>>(gcnt, bukStart, offs, N, NBUK, EP);
  k_binB<<<NBUK, 256, 0, stream>>>(staged, gcnt, bukStart, e4, offs, N);

  k_convx<<<(N * 128 / 4 + 255) / 256, 256, 0, stream>>>(x_in, xb, N * 128);
  {
    dim3 g(64, 6);
    k_convW<<<g, 256, 0, stream>>>(Wl[0], Wr[0], Wl[1], Wr[1], Wl[2], Wr[2], Wb);
  }
  k_pack<<<3, 32, 0, stream>>>(We[0], att[0], We[1], att[1], We[2], att[2], scoreTab);

  for (int l = 0; l < 3; ++l) {
    dim3 ggrid((N + 63) / 64, 2);
    k_gemm_mfma<<<ggrid, 256, 0, stream>>>(xb, Wb + (size_t)l * 32768, bl[l], br[l], xlb, xrb, N);
    int last = (l == 2) ? 1 : 0;
    const float* g = last ? bo[l] : lng[l];
    const float* b = last ? bo[l] : lnb[l];
    k_agg<<<(N * 64 + 255) / 256, 256, 0, stream>>>(xlb, xrb, e4, offs,
                                                    scoreTab + (size_t)l * 512,
                                                    bo[l], g, b,
                                                    xb, emb_out, last, N);
  }

  k_pool<<<(N + 63) / 64, 256, 0, stream>>>(emb_out, batch, pooled, N);
  k_mlp<<<G, 64, 0, stream>>>(pooled, pw1, pb1, pw2, pb2, pw3, pb3, pw4, pb4, mlp_out);
}

// Round 2
// 496.630 us; speedup vs baseline: 1.0113x; 1.0095x over previous
//
#include <hip/hip_runtime.h>
#include <math.h>

// ---------------------------------------------------------------------------
// GATv2 x3 + LN + graph max-pool + MLP.
// Round 11: k_agg only.
// (a) Pipeline deepened to records@3 / gathers@2: R10's distance-1 gather
//     gave only +5% VALUBusy -- LLC-hit latency (~450cy; xlb 12.8MB > 4MiB
//     per-XCD L2) needs ~2 compute phases of cover.
// (b) Packed-FP32 math: per-channel score/accumulate math rewritten on
//     float2 ext-vectors via __builtin_elementwise_fma/max so the backend
//     emits v_pk_fma_f32 / v_pk_max_f32 (VOP3P, 2 f32/op, gfx90a+ lineage).
//     Cuts hot-loop VALU ops ~25-30%; worst case scalarizes to R10 code.
// Everything else identical to R10 (binned CSR prepass, swapped-operand
// MFMA GEMM, packed per-lane score params).
// ---------------------------------------------------------------------------

#define LN_EPS 1e-5f
#define LOG2E 1.44269504088896340736f
#define CHUNK 4096
#define BCAP 8192  // records per staging bucket (avg 4096)

typedef short bf16x8 __attribute__((ext_vector_type(8)));
typedef float f32x4 __attribute__((ext_vector_type(4)));
typedef float f32x2 __attribute__((ext_vector_type(2)));

static __device__ __forceinline__ unsigned short f2bf(float f) {
  unsigned int u = __float_as_uint(f);
  u += 0x7fffu + ((u >> 16) & 1u);  // RNE
  return (unsigned short)(u >> 16);
}

// sum+broadcast over each 8-lane group: quad xor1, quad xor2, row_half_mirror
static __device__ __forceinline__ float dpp_sum8(float v) {
  int x;
  x = __builtin_amdgcn_update_dpp(0, __float_as_int(v), 0x0B1, 0xf, 0xf, true);  // quad_perm 1,0,3,2
  v += __int_as_float(x);
  x = __builtin_amdgcn_update_dpp(0, __float_as_int(v), 0x04E, 0xf, 0xf, true);  // quad_perm 2,3,0,1
  v += __int_as_float(x);
  x = __builtin_amdgcn_update_dpp(0, __float_as_int(v), 0x141, 0xf, 0xf, true);  // row_half_mirror
  v += __int_as_float(x);
  return v;
}

// ---------------- binned CSR build ----------------

__global__ __launch_bounds__(256) void k_binA(const int* __restrict__ ei, const float* __restrict__ ea,
                                              int* __restrict__ gcnt, float4* __restrict__ staged,
                                              int E, int nbuk) {
  __shared__ int hist[256];
  __shared__ int basebuf[256];
  int t = threadIdx.x;
  int e0 = blockIdx.x * CHUNK;

  hist[t] = 0;
  __syncthreads();
#pragma unroll
  for (int i = 0; i < CHUNK / 256; ++i) {
    int e = e0 + i * 256 + t;
    if (e < E) atomicAdd(&hist[ei[E + e] >> 8], 1);
  }
  __syncthreads();
  int h = hist[t];
  if (t < nbuk && h > 0) basebuf[t] = t * BCAP + atomicAdd(&gcnt[t], h);
  hist[t] = 0;
  __syncthreads();
#pragma unroll
  for (int i = 0; i < CHUNK / 256; ++i) {
    int e = e0 + i * 256 + t;
    if (e < E) {
      int s = ei[e];
      int d = ei[E + e];
      int b = d >> 8;
      int r = atomicAdd(&hist[b], 1);
      float4 rec;
      rec.x = ea[e * 3 + 0];
      rec.y = ea[e * 3 + 1];
      rec.z = ea[e * 3 + 2];
      rec.w = __int_as_float(s | (d << 16));
      staged[basebuf[b] + r] = rec;
    }
  }
}

__global__ void k_bscan(const int* __restrict__ gcnt, int* __restrict__ bukStart,
                        int* __restrict__ offs, int N, int nbuk, int EP) {
  __shared__ int sh[256];
  int t = threadIdx.x;
  int nodes = (t < nbuk) ? min(256, N - t * 256) : 0;
  int v = (t < nbuk) ? gcnt[t] + nodes : 0;
  sh[t] = v;
  __syncthreads();
  for (int d = 1; d < 256; d <<= 1) {
    int add = (t >= d) ? sh[t - d] : 0;
    __syncthreads();
    sh[t] += add;
    __syncthreads();
  }
  if (t < nbuk) bukStart[t] = sh[t] - v;
  if (t == 0) offs[N] = EP;
}

__global__ __launch_bounds__(256) void k_binB(const float4* __restrict__ staged,
                                              const int* __restrict__ gcnt,
                                              const int* __restrict__ bukStart,
                                              float4* __restrict__ e4,
                                              int* __restrict__ offs, int N) {
  __shared__ int hist[256], cur[256], begS[256], sh[256];
  int t = threadIdx.x;
  int b = blockIdx.x;
  int n0 = b * 256;
  int nn = min(256, N - n0);
  int m = gcnt[b];
  size_t sbase = (size_t)b * BCAP;

  hist[t] = 0;
  __syncthreads();
  for (int p = t; p < m; p += 256) {
    unsigned int u = (unsigned int)__float_as_int(staged[sbase + p].w);
    atomicAdd(&hist[(int)(u >> 16) - n0], 1);
  }
  __syncthreads();
  int v = (t < nn) ? hist[t] + 1 : 0;
  sh[t] = v;
  __syncthreads();
  for (int d = 1; d < 256; d <<= 1) {
    int add = (t >= d) ? sh[t - d] : 0;
    __syncthreads();
    sh[t] += add;
    __syncthreads();
  }
  if (t < nn) {
    int base = bukStart[b] + sh[t] - v;
    cur[t] = base;
    begS[t] = base;
    offs[n0 + t] = base;
  }
  __syncthreads();
  for (int p = t; p < m; p += 256) {
    float4 rec = staged[sbase + p];
    unsigned int u = (unsigned int)__float_as_int(rec.w);
    int pos = atomicAdd(&cur[(int)(u >> 16) - n0], 1);
    rec.w = __int_as_float((int)(u & 0xffffu) * 256);
    e4[pos] = rec;
  }
  __syncthreads();
  if (t < nn) {
    int beg = begS[t], last = cur[t];  // cur == self-loop slot after placement
    float s0 = 0.f, s1 = 0.f, s2 = 0.f;
    for (int p = beg; p < last; ++p) {
      float4 r = e4[p];
      s0 += r.x;
      s1 += r.y;
      s2 += r.z;
    }
    float invc = 1.0f / fmaxf((float)(last - beg), 1.0f);
    float4 r;
    r.x = s0 * invc;
    r.y = s1 * invc;
    r.z = s2 * invc;
    r.w = __int_as_float((n0 + t) * 256);
    e4[last] = r;
  }
}

// ---------------- converters / param packing ----------------

__global__ void k_convx(const float* __restrict__ x, unsigned short* __restrict__ xb, int n) {
  int i = (blockIdx.x * blockDim.x + threadIdx.x) * 4;
  if (i >= n) return;
  float4 v = *(const float4*)&x[i];
  ushort4 o;
  o.x = f2bf(v.x); o.y = f2bf(v.y); o.z = f2bf(v.z); o.w = f2bf(v.w);
  *(ushort4*)&xb[i] = o;
}

__global__ void k_convW(const float* __restrict__ w0, const float* __restrict__ w1,
                        const float* __restrict__ w2, const float* __restrict__ w3,
                        const float* __restrict__ w4, const float* __restrict__ w5,
                        unsigned short* __restrict__ dst) {
  const float* srcs[6] = {w0, w1, w2, w3, w4, w5};
  const float* s = srcs[blockIdx.y];
  int i = blockIdx.x * 256 + threadIdx.x;  // 0..16383
  dst[(size_t)blockIdx.y * 16384 + i] = f2bf(s[i]);
}

// per-layer, per-lane score params: tab[l][sl][16] = {wea[4], web[4], wec[4], att*LOG2E[4]}
__global__ void k_pack(const float* __restrict__ We0, const float* __restrict__ att0,
                       const float* __restrict__ We1, const float* __restrict__ att1,
                       const float* __restrict__ We2, const float* __restrict__ att2,
                       float* __restrict__ tab) {
  int l = blockIdx.x;   // 3
  int t = threadIdx.x;  // 32 (= sl)
  const float* We = (l == 0) ? We0 : ((l == 1) ? We1 : We2);
  const float* att = (l == 0) ? att0 : ((l == 1) ? att1 : att2);
  float* o = tab + (size_t)l * 512 + t * 16;
#pragma unroll
  for (int j = 0; j < 4; ++j) {
    o[j] = We[(t * 4 + j) * 3 + 0];
    o[4 + j] = We[(t * 4 + j) * 3 + 1];
    o[8 + j] = We[(t * 4 + j) * 3 + 2];
    o[12 + j] = att[t * 4 + j] * LOG2E;
  }
}

// ---------------- MFMA GEMM (swapped operands): out_bf16[n][j] = bias[j] + x[n]·W[j] ----------------
// A=W rows (channel jt*16+m), B=x rows (node row0+m); D row=channel q*4+r,
// col=node m -> lane holds 4 contiguous channels -> uint2 packed stores.
__global__ __launch_bounds__(256) void k_gemm_mfma(const unsigned short* __restrict__ xb,
                                                   const unsigned short* __restrict__ Wb,
                                                   const float* __restrict__ bl, const float* __restrict__ br,
                                                   unsigned short* __restrict__ xlb,
                                                   unsigned short* __restrict__ xrb, int N) {
  int wave = threadIdx.x >> 6;
  int lane = threadIdx.x & 63;
  int which = blockIdx.y;
  const unsigned short* W = Wb + (size_t)which * 16384;
  const float* bias = which ? br : bl;
  unsigned short* out = which ? xrb : xlb;

  int row0 = (blockIdx.x * 4 + wave) * 16;
  if (row0 >= N) return;
  int m = lane & 15;
  int q = lane >> 4;

  int brow = row0 + m;
  if (brow >= N) brow = N - 1;
  const unsigned short* xrow = xb + (size_t)brow * 128 + q * 8;

  bf16x8 bfrag[4];
#pragma unroll
  for (int kt = 0; kt < 4; ++kt) bfrag[kt] = *(const bf16x8*)(xrow + kt * 32);

  f32x4 acc[8];
#pragma unroll
  for (int jt = 0; jt < 8; ++jt) acc[jt] = (f32x4){0.f, 0.f, 0.f, 0.f};

  const unsigned short* wbase = W + (size_t)m * 128 + q * 8;
#pragma unroll
  for (int kt = 0; kt < 4; ++kt) {
#pragma unroll
    for (int jt = 0; jt < 8; ++jt) {
      bf16x8 a = *(const bf16x8*)(wbase + (size_t)jt * 16 * 128 + kt * 32);
      acc[jt] = __builtin_amdgcn_mfma_f32_16x16x32_bf16(a, bfrag[kt], acc[jt], 0, 0, 0);
    }
  }

  int node = row0 + m;
  if (node < N) {
    unsigned short* orow = out + (size_t)node * 128 + q * 4;
#pragma unroll
    for (int jt = 0; jt < 8; ++jt) {
      float4 bs = *(const float4*)&bias[jt * 16 + q * 4];
      uint2 pack;
      pack.x = (unsigned int)f2bf(acc[jt][0] + bs.x) | ((unsigned int)f2bf(acc[jt][1] + bs.y) << 16);
      pack.y = (unsigned int)f2bf(acc[jt][2] + bs.z) | ((unsigned int)f2bf(acc[jt][3] + bs.w) << 16);
      *(uint2*)(orow + jt * 16) = pack;
    }
  }
}

// ---------------- fused: score + softmax(exp2) + weighted agg + epilogue ----------------
// one wave per node; lanes 0-31 = edge p, lanes 32-63 = edge p+1 (same node);
// each lane owns 4 channels c = (lane&31)*4; head group = 8 lanes.
// R11: 3-deep record / 2-deep gather pipeline + packed-f32 (v_pk_*) math.
__global__ __launch_bounds__(256) void k_agg(const unsigned short* __restrict__ xlb,
                                             const unsigned short* __restrict__ xrb,
                                             const float4* __restrict__ e4,
                                             const int* __restrict__ offs,
                                             const float* __restrict__ scoreTab,
                                             const float* __restrict__ bo,
                                             const float* __restrict__ lng, const float* __restrict__ lnb,
                                             unsigned short* __restrict__ xnext_bf,
                                             float* __restrict__ emb, int last, int N) {
  int w = (blockIdx.x * blockDim.x + threadIdx.x) >> 6;
  if (w >= N) return;
  int lane = threadIdx.x & 63;
  int half = lane >> 5;
  int sl = lane & 31;
  int c = sl * 4;
  unsigned int c2 = (unsigned int)(c * 2);  // byte offset into bf16 row
  int beg = offs[w], end = offs[w + 1];
  int cnt = end - beg;

  // packed per-lane params as float2 halves (channels 01 / 23)
  f32x2 xr01, xr23, wea01, wea23, web01, web23, wec01, wec23, at01, at23;
  {
    const float4* tp = (const float4*)(scoreTab + (size_t)sl * 16);
    float4 pa = tp[0], pb = tp[1], pc = tp[2], pt = tp[3];
    wea01[0] = pa.x; wea01[1] = pa.y; wea23[0] = pa.z; wea23[1] = pa.w;
    web01[0] = pb.x; web01[1] = pb.y; web23[0] = pb.z; web23[1] = pb.w;
    wec01[0] = pc.x; wec01[1] = pc.y; wec23[0] = pc.z; wec23[1] = pc.w;
    at01[0] = pt.x; at01[1] = pt.y; at23[0] = pt.z; at23[1] = pt.w;
    uint2 vr = *(const uint2*)&xrb[(size_t)w * 128 + c];
    xr01[0] = __uint_as_float(vr.x << 16);
    xr01[1] = __uint_as_float(vr.x & 0xffff0000u);
    xr23[0] = __uint_as_float(vr.y << 16);
    xr23[1] = __uint_as_float(vr.y & 0xffff0000u);
  }

  const char* xlB = (const char*)xlb;
  const char* e4B = (const char*)e4;
  unsigned int lastoff = (unsigned int)(end - 1) << 4;

  float l = 0.f;
  f32x2 acc01 = {0.f, 0.f}, acc23 = {0.f, 0.f};

  int T = (cnt + 1) >> 1;  // pair iterations

  // ---- pipeline prologue: records for pairs 0..2, gathers for pairs 0..1 ----
  unsigned int o0 = (unsigned int)(beg + half) << 4;
  if (o0 > lastoff) o0 = lastoff;  // cnt==1, half 1 clamps
  unsigned int o1 = o0 + 32u;
  if (o1 > lastoff) o1 = lastoff;
  unsigned int o2 = o1 + 32u;
  if (o2 > lastoff) o2 = lastoff;
  float4 e0 = *(const float4*)(e4B + o0);
  float4 e1 = *(const float4*)(e4B + o1);
  float4 e2 = *(const float4*)(e4B + o2);
  uint2 g0 = *(const uint2*)(xlB + ((unsigned int)__float_as_int(e0.w) + c2));
  uint2 g1 = *(const uint2*)(xlB + ((unsigned int)__float_as_int(e1.w) + c2));
  unsigned int offP = o2;

  // one edge: unpack gather, score (packed f32), exp2, accumulate.
  auto compute = [&](const float4& e, uint2 v, bool valid) {
    f32x2 xl01, xl23;
    xl01[0] = __uint_as_float(v.x << 16);
    xl01[1] = __uint_as_float(v.x & 0xffff0000u);
    xl23[0] = __uint_as_float(v.y << 16);
    xl23[1] = __uint_as_float(v.y & 0xffff0000u);
    f32x2 ex = {e.x, e.x}, ey = {e.y, e.y}, ez = {e.z, e.z};
    f32x2 t01 = __builtin_elementwise_fma(wea01, ex,
                  __builtin_elementwise_fma(web01, ey,
                    __builtin_elementwise_fma(wec01, ez, xr01 + xl01)));
    f32x2 t23 = __builtin_elementwise_fma(wea23, ex,
                  __builtin_elementwise_fma(web23, ey,
                    __builtin_elementwise_fma(wec23, ez, xr23 + xl23)));
    t01 = __builtin_elementwise_max(t01, t01 * 0.2f);
    t23 = __builtin_elementwise_max(t23, t23 * 0.2f);
    f32x2 d2 = __builtin_elementwise_fma(t01, at01, t23 * at23);
    float s = d2[0] + d2[1];
    float wgt = __builtin_amdgcn_exp2f(dpp_sum8(s));
    if (!valid) wgt = 0.f;
    l += wgt;
    f32x2 w2 = {wgt, wgt};
    acc01 = __builtin_elementwise_fma(xl01, w2, acc01);
    acc23 = __builtin_elementwise_fma(xl23, w2, acc23);
  };

  // ---- steady state: record(i+3), gather(i+2), compute(i) ----
#pragma unroll 2
  for (int it = 0; it < T - 3; ++it) {
    unsigned int o3 = offP + 32u;
    if (o3 > lastoff) o3 = lastoff;
    float4 e3 = *(const float4*)(e4B + o3);
    uint2 g2 = *(const uint2*)(xlB + ((unsigned int)__float_as_int(e2.w) + c2));
    compute(e0, g0, true);
    e0 = e1; e1 = e2; e2 = e3;
    g0 = g1; g1 = g2;
    offP = o3;
  }
  if (T >= 3) {  // pair T-3: issue last gather, compute
    uint2 g2 = *(const uint2*)(xlB + ((unsigned int)__float_as_int(e2.w) + c2));
    compute(e0, g0, true);
    e0 = e1; e1 = e2;
    g0 = g1; g1 = g2;
  }
  if (T >= 2) {  // pair T-2 (always fully valid)
    compute(e0, g0, true);
    e0 = e1;
    g0 = g1;
  }
  {  // pair T-1 (masked: odd cnt leaves half==1 invalid)
    int idx = 2 * (T - 1) + half;
    compute(e0, g0, idx < cnt);
  }

  // combine halves
  l += __shfl_xor(l, 32);
  float a0 = acc01[0]; a0 += __shfl_xor(a0, 32);
  float a1 = acc01[1]; a1 += __shfl_xor(a1, 32);
  float a2 = acc23[0]; a2 += __shfl_xor(a2, 32);
  float a3 = acc23[1]; a3 += __shfl_xor(a3, 32);

  float inv = 1.0f / l;
  f32x4 o;
  const float4 bo4 = *(const float4*)&bo[c];
  o[0] = a0 * inv + bo4.x;
  o[1] = a1 * inv + bo4.y;
  o[2] = a2 * inv + bo4.z;
  o[3] = a3 * inv + bo4.w;

  if (last) {
    if (half == 0) {
      float4 st = {o[0], o[1], o[2], o[3]};
      *(float4*)&emb[(size_t)w * 128 + c] = st;
    }
  } else {
    f32x4 r;
    r[0] = fmaxf(o[0], 0.f);
    r[1] = fmaxf(o[1], 0.f);
    r[2] = fmaxf(o[2], 0.f);
    r[3] = fmaxf(o[3], 0.f);
    float s = r[0] + r[1] + r[2] + r[3];
    s += __shfl_xor(s, 1);
    s += __shfl_xor(s, 2);
    s += __shfl_xor(s, 4);
    s += __shfl_xor(s, 8);
    s += __shfl_xor(s, 16);
    float mu = s * 0.0078125f;  // /128
    f32x4 d;
    d[0] = r[0] - mu;
    d[1] = r[1] - mu;
    d[2] = r[2] - mu;
    d[3] = r[3] - mu;
    float v2 = d[0] * d[0] + d[1] * d[1] + d[2] * d[2] + d[3] * d[3];
    v2 += __shfl_xor(v2, 1);
    v2 += __shfl_xor(v2, 2);
    v2 += __shfl_xor(v2, 4);
    v2 += __shfl_xor(v2, 8);
    v2 += __shfl_xor(v2, 16);
    float var = v2 * 0.0078125f;
    float rstd = rsqrtf(var + LN_EPS);
    if (half == 0) {
      const float4 g4 = *(const float4*)&lng[c];
      const float4 b4 = *(const float4*)&lnb[c];
      float o0 = d[0] * rstd * g4.x + b4.x;
      float o1 = d[1] * rstd * g4.y + b4.y;
      float o2 = d[2] * rstd * g4.z + b4.z;
      float o3 = d[3] * rstd * g4.w + b4.w;
      uint2 pack;
      pack.x = (unsigned int)f2bf(o0) | ((unsigned int)f2bf(o1) << 16);
      pack.y = (unsigned int)f2bf(o2) | ((unsigned int)f2bf(o3) << 16);
      *(uint2*)&xnext_bf[(size_t)w * 128 + c] = pack;
    }
  }
}

// ---------------- graph max-pool (relu implicit: atomicMax vs 0-init) ----------------
__global__ void k_pool(const float* __restrict__ emb, const int* __restrict__ batch,
                       float* __restrict__ pooled, int N) {
  int c = threadIdx.x & 127;
  int half = threadIdx.x >> 7;
  int base = blockIdx.x * 64 + half;
  int limit = min(blockIdx.x * 64 + 64, N);
  float cur = 0.f;
  int curg = -1;
  for (int n = base; n < limit; n += 2) {
    int g = batch[n];
    if (g != curg) {
      if (curg >= 0) atomicMax((unsigned int*)&pooled[curg * 128 + c], __float_as_uint(cur));
      curg = g;
      cur = 0.f;
    }
    cur = fmaxf(cur, emb[(size_t)n * 128 + c]);
  }
  if (curg >= 0) atomicMax((unsigned int*)&pooled[curg * 128 + c], __float_as_uint(cur));
}

// ---------------- MLP: 128 -> 32 -> 32 -> 32 -> 1 ----------------
__global__ void k_mlp(const float* __restrict__ pooled,
                      const float* __restrict__ pw1, const float* __restrict__ pb1,
                      const float* __restrict__ pw2, const float* __restrict__ pb2,
                      const float* __restrict__ pw3, const float* __restrict__ pb3,
                      const float* __restrict__ pw4, const float* __restrict__ pb4,
                      float* __restrict__ out) {
  int g = blockIdx.x;
  int t = threadIdx.x;  // 64 threads
  __shared__ float buf1[32], buf2[32];
  if (t < 32) {
    float acc = pb1[t];
    for (int k = 0; k < 128; ++k) acc += pw1[t * 128 + k] * pooled[g * 128 + k];
    buf1[t] = fmaxf(acc, 0.f);
  }
  __syncthreads();
  if (t < 32) {
    float acc = pb2[t];
    for (int k = 0; k < 32; ++k) acc += pw2[t * 32 + k] * buf1[k];
    buf2[t] = fmaxf(acc, 0.f);
  }
  __syncthreads();
  if (t < 32) {
    float acc = pb3[t];
    for (int k = 0; k < 32; ++k) acc += pw3[t * 32 + k] * buf2[k];
    buf1[t] = fmaxf(acc, 0.f);
  }
  __syncthreads();
  if (t == 0) {
    float acc = pb4[0];
    for (int k = 0; k < 32; ++k) acc += pw4[k] * buf1[k];
    out[g] = acc;
  }
}

// ---------------------------------------------------------------------------

extern "C" void kernel_launch(void* const* d_in, const int* in_sizes, int n_in,
                              void* d_out, int out_size, void* d_ws, size_t ws_size,
                              hipStream_t stream) {
  const float* x_in = (const float*)d_in[0];
  const int* ei = (const int*)d_in[1];
  const int* batch = (const int*)d_in[2];
  const float* ea = (const float*)d_in[3];

  const int N = in_sizes[0] / 128;
  const int E = in_sizes[1] / 2;
  const int EP = E + N;
  const int G = out_size - N * 128;
  const int NBUK = (N + 255) / 256;

  const float *Wl[3], *bl[3], *Wr[3], *br[3], *We[3], *att[3], *bo[3];
  for (int l = 0; l < 3; ++l) {
    Wl[l] = (const float*)d_in[4 + 7 * l];
    bl[l] = (const float*)d_in[5 + 7 * l];
    Wr[l] = (const float*)d_in[6 + 7 * l];
    br[l] = (const float*)d_in[7 + 7 * l];
    We[l] = (const float*)d_in[8 + 7 * l];
    att[l] = (const float*)d_in[9 + 7 * l];
    bo[l] = (const float*)d_in[10 + 7 * l];
  }
  const float* lng[2] = {(const float*)d_in[25], (const float*)d_in[27]};
  const float* lnb[2] = {(const float*)d_in[26], (const float*)d_in[28]};
  const float* pw1 = (const float*)d_in[29];
  const float* pb1 = (const float*)d_in[30];
  const float* pw2 = (const float*)d_in[31];
  const float* pb2 = (const float*)d_in[32];
  const float* pw3 = (const float*)d_in[33];
  const float* pb3 = (const float*)d_in[34];
  const float* pw4 = (const float*)d_in[35];
  const float* pb4 = (const float*)d_in[36];

  char* base = (char*)d_ws;
  size_t cur = 0;
  auto carve = [&](size_t bytes) -> char* {
    char* p = base + cur;
    cur += (bytes + 255) & ~(size_t)255;
    return p;
  };
  unsigned short* xlb = (unsigned short*)carve((size_t)N * 128 * 2);
  unsigned short* xrb = (unsigned short*)carve((size_t)N * 128 * 2);
  unsigned short* xb = (unsigned short*)carve((size_t)N * 128 * 2);  // bf16 activations
  unsigned short* Wb = (unsigned short*)carve((size_t)6 * 16384 * 2);
  float4* e4 = (float4*)carve((size_t)EP * 16);
  float4* staged = (float4*)carve((size_t)NBUK * BCAP * 16);
  int* offs = (int*)carve((size_t)(N + 1) * 4);
  int* gcnt = (int*)carve((size_t)NBUK * 4);
  int* bukStart = (int*)carve((size_t)(NBUK + 1) * 4);
  float* scoreTab = (float*)carve((size_t)3 * 512 * 4);
  float* pooled = (float*)carve((size_t)G * 128 * 4);

  float* emb_out = (float*)d_out;
  float* mlp_out = (float*)d_out + (size_t)N * 128;

  hipMemsetAsync(gcnt, 0, (size_t)NBUK * 4, stream);
  hipMemsetAsync(pooled, 0, (size_t)G * 128 * 4, stream);

  k_binA<<<(E + CHUNK - 1) / CHUNK, 256, 0, stream>>>(ei, ea, gcnt, staged, E, NBUK);
  k_bscan<<<1, 256, 0, stream>>>(gcnt, bukStart, offs, N, NBUK, EP);
  k_binB<<<NBUK, 256, 0, stream>>>(staged, gcnt, bukStart, e4, offs, N);

  k_convx<<<(N * 128 / 4 + 255) / 256, 256, 0, stream>>>(x_in, xb, N * 128);
  {
    dim3 g(64, 6);
    k_convW<<<g, 256, 0, stream>>>(Wl[0], Wr[0], Wl[1], Wr[1], Wl[2], Wr[2], Wb);
  }
  k_pack<<<3, 32, 0, stream>>>(We[0], att[0], We[1], att[1], We[2], att[2], scoreTab);

  for (int l = 0; l < 3; ++l) {
    dim3 ggrid((N + 63) / 64, 2);
    k_gemm_mfma<<<ggrid, 256, 0, stream>>>(xb, Wb + (size_t)l * 32768, bl[l], br[l], xlb, xrb, N);
    int last = (l == 2) ? 1 : 0;
    const float* g = last ? bo[l] : lng[l];
    const float* b = last ? bo[l] : lnb[l];
    k_agg<<<(N * 64 + 255) / 256, 256, 0, stream>>>(xlb, xrb, e4, offs,
                                                    scoreTab + (size_t)l * 512,
                                                    bo[l], g, b,
                                                    xb, emb_out, last, N);
  }

  k_pool<<<(N + 63) / 64, 256, 0, stream>>>(emb_out, batch, pooled, N);
  k_mlp<<<G, 64, 0, stream>>>(pooled, pw1, pb1, pw2, pb2, pw3, pb3, pw4, pb4, mlp_out);
}